// Round 1
// baseline (122.063 us; speedup 1.0000x reference)
//
#include <hip/hip_runtime.h>
#include <math.h>

#define NF 256      // in_features
#define NT 256      // num_trees
#define ND 6        // depth
#define NB 2048     // batch
#define NCOL (NT * ND)   // 1536
#define NLEAF 64         // 2^depth

// ---------------------------------------------------------------------------
// Kernel 1: sparsemax over the feature axis for each (tree, depth) column.
// fsl layout: [F, T, D] row-major = [256, 1536]; column `col` = (t*D + d).
// One block (256 threads) per column; thread i owns feature i.
// ---------------------------------------------------------------------------
__global__ __launch_bounds__(256) void sparsemax_kernel(
    const float* __restrict__ fsl,   // [NF, NCOL]
    float* __restrict__ fs)          // [NF, NCOL] (same layout)
{
    __shared__ float s[NF];
    __shared__ int wk[4];
    const int col = blockIdx.x;
    const int tid = threadIdx.x;

    const float v = fsl[tid * NCOL + col];

    // ---- max reduce ----
    s[tid] = v;
    __syncthreads();
    for (int off = 128; off > 0; off >>= 1) {
        if (tid < off) s[tid] = fmaxf(s[tid], s[tid + off]);
        __syncthreads();
    }
    const float xmax = s[0];
    __syncthreads();

    const float xs = v - xmax;

    // ---- bitonic sort (descending) of xs in LDS ----
    s[tid] = xs;
    __syncthreads();
    for (int k = 2; k <= NF; k <<= 1) {
        for (int j = k >> 1; j > 0; j >>= 1) {
            const int ixj = tid ^ j;
            if (ixj > tid) {
                const float a = s[tid];
                const float b = s[ixj];
                const bool desc = ((tid & k) == 0);
                const bool do_swap = desc ? (a < b) : (a > b);
                if (do_swap) { s[tid] = b; s[ixj] = a; }
            }
            __syncthreads();
        }
    }
    const float z = s[tid];   // sorted descending, thread i holds z[i]

    // ---- inclusive scan (cumsum) in place ----
    for (int off = 1; off < NF; off <<= 1) {
        const float tmp = (tid >= off) ? s[tid - off] : 0.0f;
        __syncthreads();
        s[tid] += tmp;
        __syncthreads();
    }
    const float cs = s[tid];  // cumsum of z through index tid

    // ---- support size k (support flags are a prefix since z descending) ----
    const bool flag = ((float)(tid + 1) * z > cs - 1.0f);
    const unsigned long long m = __ballot(flag);
    const int lane = tid & 63;
    const int wave = tid >> 6;
    if (lane == 0) wk[wave] = __popcll(m);
    __syncthreads();
    const int k = wk[0] + wk[1] + wk[2] + wk[3];

    const float tau = (s[k - 1] - 1.0f) / (float)k;
    fs[tid * NCOL + col] = fmaxf(xs - tau, 0.0f);
}

// ---------------------------------------------------------------------------
// Kernel 2: fp32 GEMM  fv[B, NCOL] = x[B, NF] @ fs[NF, NCOL]
// 64x64 block tile, BK=16, 256 threads, 4x4 micro-tile per thread.
// ---------------------------------------------------------------------------
#define BM 64
#define BN 64
#define BK 16

__global__ __launch_bounds__(256) void gemm_kernel(
    const float* __restrict__ A,   // [NB, NF]
    const float* __restrict__ Bm,  // [NF, NCOL]
    float* __restrict__ C)         // [NB, NCOL]
{
    __shared__ float As[BK][BM + 4];
    __shared__ float Bs[BK][BN + 4];

    const int tid = threadIdx.x;
    const int tx = tid & 15;        // n direction
    const int ty = tid >> 4;        // m direction
    const int bn0 = blockIdx.x * BN;
    const int bm0 = blockIdx.y * BM;

    float acc[4][4] = {};

    for (int k0 = 0; k0 < NF; k0 += BK) {
        // A tile: 64 rows x 16 k, one float4 per thread, store transposed
        {
            const int row = tid >> 2;          // 0..63
            const int kq  = (tid & 3) * 4;     // 0,4,8,12
            const float4 av = *(const float4*)&A[(bm0 + row) * NF + k0 + kq];
            As[kq + 0][row] = av.x;
            As[kq + 1][row] = av.y;
            As[kq + 2][row] = av.z;
            As[kq + 3][row] = av.w;
        }
        // B tile: 16 k x 64 cols, one float4 per thread, direct store
        {
            const int row = tid >> 4;          // 0..15
            const int c4  = (tid & 15) * 4;    // 0..60
            const float4 bv = *(const float4*)&Bm[(k0 + row) * NCOL + bn0 + c4];
            *(float4*)&Bs[row][c4] = bv;
        }
        __syncthreads();

        #pragma unroll
        for (int kk = 0; kk < BK; kk++) {
            const float4 a4 = *(const float4*)&As[kk][ty * 4];
            const float4 b4 = *(const float4*)&Bs[kk][tx * 4];
            const float ar[4] = {a4.x, a4.y, a4.z, a4.w};
            const float br[4] = {b4.x, b4.y, b4.z, b4.w};
            #pragma unroll
            for (int i = 0; i < 4; i++)
                #pragma unroll
                for (int j = 0; j < 4; j++)
                    acc[i][j] = fmaf(ar[i], br[j], acc[i][j]);
        }
        __syncthreads();
    }

    #pragma unroll
    for (int i = 0; i < 4; i++) {
        const int mrow = bm0 + ty * 4 + i;
        const float4 o = make_float4(acc[i][0], acc[i][1], acc[i][2], acc[i][3]);
        *(float4*)&C[mrow * NCOL + bn0 + tx * 4] = o;
    }
}

// ---------------------------------------------------------------------------
// Kernel 3: per-(batch, tree) decision-tree evaluation.
// block = batch row, thread = tree.
// ---------------------------------------------------------------------------
__global__ __launch_bounds__(256) void tree_kernel(
    const float* __restrict__ fv,     // [NB, NT, ND]
    const float* __restrict__ thr,    // [NT, ND]
    const float* __restrict__ ltemp,  // [NT, ND]
    const float* __restrict__ resp,   // [NT, 1, NLEAF]
    float* __restrict__ out)          // [NB, NT]
{
    const int b = blockIdx.x;
    const int t = threadIdx.x;

    float sp[ND], sm[ND];
    #pragma unroll
    for (int d = 0; d < ND; d++) {
        const float f  = fv[b * NCOL + t * ND + d];
        const float tl = (f - thr[t * ND + d]) * expf(-ltemp[t * ND + d]);
        const float h  = 0.5f * tl;
        sp[d] = fminf(fmaxf(0.5f + h, 0.0f), 1.0f);  // sparsemoid(tl)  -> bit==0
        sm[d] = fminf(fmaxf(0.5f - h, 0.0f), 1.0f);  // sparsemoid(-tl) -> bit==1
    }

    // leaf weights via iterative doubling: W[c] = prod_d (bit_d(c) ? sm[d] : sp[d])
    float w[NLEAF];
    w[0] = 1.0f;
    #pragma unroll
    for (int d = 0; d < ND; d++) {
        const int half = 1 << d;
        #pragma unroll
        for (int c = 0; c < (1 << ND) / 2; c++) {   // upper bound; guard below
            if (c < half) {
                const float base = w[c];
                w[c + half] = base * sm[d];
                w[c]        = base * sp[d];
            }
        }
    }

    float acc = 0.0f;
    #pragma unroll
    for (int c = 0; c < NLEAF; c++)
        acc = fmaf(w[c], resp[t * NLEAF + c], acc);

    out[b * NT + t] = acc;
}

// ---------------------------------------------------------------------------
extern "C" void kernel_launch(void* const* d_in, const int* in_sizes, int n_in,
                              void* d_out, int out_size, void* d_ws, size_t ws_size,
                              hipStream_t stream)
{
    const float* x    = (const float*)d_in[0];  // [2048, 256]
    const float* resp = (const float*)d_in[1];  // [256, 1, 64]
    const float* fsl  = (const float*)d_in[2];  // [256, 256, 6]
    const float* thr  = (const float*)d_in[3];  // [256, 6]
    const float* lt   = (const float*)d_in[4];  // [256, 6]
    float* out = (float*)d_out;                 // [2048, 256]

    float* fs = (float*)d_ws;                   // [256, 1536]
    float* fv = fs + (size_t)NF * NCOL;         // [2048, 1536]

    sparsemax_kernel<<<NCOL, 256, 0, stream>>>(fsl, fs);

    dim3 g(NCOL / BN, NB / BM);
    gemm_kernel<<<g, 256, 0, stream>>>(x, fs, fv);

    tree_kernel<<<NB, 256, 0, stream>>>(fv, thr, lt, resp, out);
}

// Round 2
// 110.760 us; speedup vs baseline: 1.1020x; 1.1020x over previous
//
#include <hip/hip_runtime.h>
#include <math.h>

#define NF 256      // in_features
#define NT 256      // num_trees
#define ND 6        // depth
#define NB 2048     // batch
#define NCOL (NT * ND)   // 1536
#define NLEAF 64         // 2^depth

typedef __attribute__((ext_vector_type(8))) short bf16x8;         // MFMA A/B frag (4 VGPRs)
typedef __attribute__((ext_vector_type(4))) float f32x4;          // MFMA C/D frag
typedef __attribute__((ext_vector_type(8))) unsigned short u16x8; // 16B staging chunk

__device__ inline unsigned short f2bf(float f) {   // round-to-nearest-even bf16
    unsigned u = __float_as_uint(f);
    u += 0x7fffu + ((u >> 16) & 1u);
    return (unsigned short)(u >> 16);
}
__device__ inline float bf2f(unsigned short h) {
    return __uint_as_float(((unsigned)h) << 16);
}

// ---------------------------------------------------------------------------
// Kernel 0: split x[B,F] fp32 into bf16 hi/lo pair (same layout).
// ---------------------------------------------------------------------------
__global__ __launch_bounds__(256) void convert_x_kernel(
    const float* __restrict__ x,
    unsigned short* __restrict__ xh,
    unsigned short* __restrict__ xl)
{
    const int i = (blockIdx.x * 256 + threadIdx.x) * 4;
    const float4 v = *(const float4*)&x[i];
    const unsigned short h0 = f2bf(v.x), h1 = f2bf(v.y), h2 = f2bf(v.z), h3 = f2bf(v.w);
    *(ushort4*)&xh[i] = make_ushort4(h0, h1, h2, h3);
    *(ushort4*)&xl[i] = make_ushort4(f2bf(v.x - bf2f(h0)), f2bf(v.y - bf2f(h1)),
                                     f2bf(v.z - bf2f(h2)), f2bf(v.w - bf2f(h3)));
}

// ---------------------------------------------------------------------------
// Kernel 1: sparsemax over the feature axis for each (tree, depth) column.
// Input fsl layout [F, T*D]; output TRANSPOSED [col][feature] bf16 hi/lo
// (coalesced writes; GEMM B-operand wants n-major, k-contiguous).
// ---------------------------------------------------------------------------
__global__ __launch_bounds__(256) void sparsemax_kernel(
    const float* __restrict__ fsl,       // [NF, NCOL]
    unsigned short* __restrict__ fs_hi,  // [NCOL, NF]
    unsigned short* __restrict__ fs_lo)  // [NCOL, NF]
{
    __shared__ float s[NF];
    __shared__ int wk[4];
    const int col = blockIdx.x;
    const int tid = threadIdx.x;

    const float v = fsl[tid * NCOL + col];

    // ---- max reduce ----
    s[tid] = v;
    __syncthreads();
    for (int off = 128; off > 0; off >>= 1) {
        if (tid < off) s[tid] = fmaxf(s[tid], s[tid + off]);
        __syncthreads();
    }
    const float xmax = s[0];
    __syncthreads();

    const float xs = v - xmax;

    // ---- bitonic sort (descending) of xs in LDS ----
    s[tid] = xs;
    __syncthreads();
    for (int k = 2; k <= NF; k <<= 1) {
        for (int j = k >> 1; j > 0; j >>= 1) {
            const int ixj = tid ^ j;
            if (ixj > tid) {
                const float a = s[tid];
                const float b = s[ixj];
                const bool desc = ((tid & k) == 0);
                if (desc ? (a < b) : (a > b)) { s[tid] = b; s[ixj] = a; }
            }
            __syncthreads();
        }
    }
    const float z = s[tid];   // sorted descending

    // ---- inclusive scan (cumsum) in place ----
    for (int off = 1; off < NF; off <<= 1) {
        const float tmp = (tid >= off) ? s[tid - off] : 0.0f;
        __syncthreads();
        s[tid] += tmp;
        __syncthreads();
    }

    // ---- support size k ----
    const bool flag = ((float)(tid + 1) * z > s[tid] - 1.0f);
    const unsigned long long m = __ballot(flag);
    if ((tid & 63) == 0) wk[tid >> 6] = __popcll(m);
    __syncthreads();
    const int k = wk[0] + wk[1] + wk[2] + wk[3];

    const float tau = (s[k - 1] - 1.0f) / (float)k;
    const float val = fmaxf(xs - tau, 0.0f);
    const unsigned short h = f2bf(val);
    fs_hi[col * NF + tid] = h;
    fs_lo[col * NF + tid] = f2bf(val - bf2f(h));
}

// ---------------------------------------------------------------------------
// Kernel 2: split-bf16 MFMA GEMM  fv[B, NCOL] = x[B, NF] @ fs[NF, NCOL]
// A = x hi/lo [NB, NF]; B = fs TRANSPOSED hi/lo [NCOL, NF].
// acc = Ah*Bh + Ah*Bl + Al*Bh  (lo*lo dropped; rel err ~2^-18).
// 64x64 block tile, 4 waves in 2x2, each wave 2x2 16x16x32 MFMA tiles, BK=32.
// ---------------------------------------------------------------------------
#define TM 64
#define TN 64
#define TK 32

__global__ __launch_bounds__(256) void gemm_mfma_kernel(
    const unsigned short* __restrict__ Ah, const unsigned short* __restrict__ Al,
    const unsigned short* __restrict__ Bh, const unsigned short* __restrict__ Bl,
    float* __restrict__ C)
{
    __shared__ unsigned short sAh[TM][TK], sAl[TM][TK];
    __shared__ unsigned short sBh[TN][TK], sBl[TN][TK];

    const int tid  = threadIdx.x;
    const int lane = tid & 63;
    const int w    = tid >> 6;
    const int wm   = w & 1;          // wave M position (0..1)
    const int wn   = w >> 1;         // wave N position (0..1)
    const int bm0  = blockIdx.y * TM;
    const int bn0  = blockIdx.x * TN;

    const int l15  = lane & 15;
    const int quad = lane >> 4;

    // staging: thread i copies one 16B chunk per tile; tile = 64 rows x 32 k
    const int srow  = tid >> 2;
    const int skseg = (tid & 3) * 8;

    f32x4 acc[2][2] = {};

    for (int k0 = 0; k0 < NF; k0 += TK) {
        *(u16x8*)&sAh[srow][skseg] = *(const u16x8*)&Ah[(bm0 + srow) * NF + k0 + skseg];
        *(u16x8*)&sAl[srow][skseg] = *(const u16x8*)&Al[(bm0 + srow) * NF + k0 + skseg];
        *(u16x8*)&sBh[srow][skseg] = *(const u16x8*)&Bh[(bn0 + srow) * NF + k0 + skseg];
        *(u16x8*)&sBl[srow][skseg] = *(const u16x8*)&Bl[(bn0 + srow) * NF + k0 + skseg];
        __syncthreads();

        #pragma unroll
        for (int im = 0; im < 2; im++) {
            const bf16x8 a_h = *(const bf16x8*)&sAh[wm * 32 + im * 16 + l15][quad * 8];
            const bf16x8 a_l = *(const bf16x8*)&sAl[wm * 32 + im * 16 + l15][quad * 8];
            #pragma unroll
            for (int in = 0; in < 2; in++) {
                const bf16x8 b_h = *(const bf16x8*)&sBh[wn * 32 + in * 16 + l15][quad * 8];
                const bf16x8 b_l = *(const bf16x8*)&sBl[wn * 32 + in * 16 + l15][quad * 8];
                acc[im][in] = __builtin_amdgcn_mfma_f32_16x16x32_bf16(a_h, b_h, acc[im][in], 0, 0, 0);
                acc[im][in] = __builtin_amdgcn_mfma_f32_16x16x32_bf16(a_h, b_l, acc[im][in], 0, 0, 0);
                acc[im][in] = __builtin_amdgcn_mfma_f32_16x16x32_bf16(a_l, b_h, acc[im][in], 0, 0, 0);
            }
        }
        __syncthreads();
    }

    // epilogue: C/D mapping — row = quad*4 + reg, col = lane&15
    #pragma unroll
    for (int im = 0; im < 2; im++)
        #pragma unroll
        for (int in = 0; in < 2; in++)
            #pragma unroll
            for (int r = 0; r < 4; r++) {
                const int m = bm0 + wm * 32 + im * 16 + quad * 4 + r;
                const int n = bn0 + wn * 32 + in * 16 + l15;
                C[m * NCOL + n] = acc[im][in][r];
            }
}

// ---------------------------------------------------------------------------
// Kernel 3: per-(batch, tree) decision-tree evaluation.
// ---------------------------------------------------------------------------
__global__ __launch_bounds__(256) void tree_kernel(
    const float* __restrict__ fv,     // [NB, NT*ND]
    const float* __restrict__ thr,    // [NT, ND]
    const float* __restrict__ ltemp,  // [NT, ND]
    const float* __restrict__ resp,   // [NT, 1, NLEAF]
    float* __restrict__ out)          // [NB, NT]
{
    const int b = blockIdx.x;
    const int t = threadIdx.x;

    float sp[ND], sm[ND];
    #pragma unroll
    for (int d = 0; d < ND; d++) {
        const float f  = fv[b * NCOL + t * ND + d];
        const float tl = (f - thr[t * ND + d]) * expf(-ltemp[t * ND + d]);
        const float h  = 0.5f * tl;
        sp[d] = fminf(fmaxf(0.5f + h, 0.0f), 1.0f);  // sparsemoid(tl)  -> bit==0
        sm[d] = fminf(fmaxf(0.5f - h, 0.0f), 1.0f);  // sparsemoid(-tl) -> bit==1
    }

    float wleaf[NLEAF];
    wleaf[0] = 1.0f;
    #pragma unroll
    for (int d = 0; d < ND; d++) {
        const int half = 1 << d;
        #pragma unroll
        for (int c = 0; c < NLEAF / 2; c++) {
            if (c < half) {
                const float base = wleaf[c];
                wleaf[c + half] = base * sm[d];
                wleaf[c]        = base * sp[d];
            }
        }
    }

    float acc = 0.0f;
    #pragma unroll
    for (int c = 0; c < NLEAF; c++)
        acc = fmaf(wleaf[c], resp[t * NLEAF + c], acc);

    out[b * NT + t] = acc;
}

// ---------------------------------------------------------------------------
extern "C" void kernel_launch(void* const* d_in, const int* in_sizes, int n_in,
                              void* d_out, int out_size, void* d_ws, size_t ws_size,
                              hipStream_t stream)
{
    const float* x    = (const float*)d_in[0];  // [2048, 256]
    const float* resp = (const float*)d_in[1];  // [256, 1, 64]
    const float* fsl  = (const float*)d_in[2];  // [256, 256*6]
    const float* thr  = (const float*)d_in[3];  // [256, 6]
    const float* lt   = (const float*)d_in[4];  // [256, 6]
    float* out = (float*)d_out;                 // [2048, 256]

    // workspace layout
    float* fv = (float*)d_ws;                               // [NB, NCOL] fp32
    unsigned short* xh    = (unsigned short*)(fv + (size_t)NB * NCOL);
    unsigned short* xl    = xh + (size_t)NB * NF;
    unsigned short* fs_hi = xl + (size_t)NB * NF;           // [NCOL, NF]
    unsigned short* fs_lo = fs_hi + (size_t)NCOL * NF;

    convert_x_kernel<<<NB * NF / (256 * 4), 256, 0, stream>>>(x, xh, xl);
    sparsemax_kernel<<<NCOL, 256, 0, stream>>>(fsl, fs_hi, fs_lo);

    dim3 g(NCOL / TN, NB / TM);
    gemm_mfma_kernel<<<g, 256, 0, stream>>>(xh, xl, fs_hi, fs_lo, fv);

    tree_kernel<<<NB, 256, 0, stream>>>(fv, thr, lt, resp, out);
}

// Round 3
// 89.822 us; speedup vs baseline: 1.3590x; 1.2331x over previous
//
#include <hip/hip_runtime.h>
#include <math.h>

#define NF 256      // in_features
#define NT 256      // num_trees
#define ND 6        // depth
#define NB 2048     // batch
#define NCOL (NT * ND)   // 1536
#define NLEAF 64         // 2^depth

typedef __attribute__((ext_vector_type(8))) short bf16x8;         // MFMA A/B frag
typedef __attribute__((ext_vector_type(4))) float f32x4;          // MFMA C/D frag
typedef __attribute__((ext_vector_type(8))) unsigned short u16x8; // 16B chunk

__device__ inline unsigned short f2bf(float f) {   // round-to-nearest-even bf16
    unsigned u = __float_as_uint(f);
    u += 0x7fffu + ((u >> 16) & 1u);
    return (unsigned short)(u >> 16);
}
__device__ inline float bf2f(unsigned short h) {
    return __uint_as_float(((unsigned)h) << 16);
}

// ---------------------------------------------------------------------------
// Kernel 1: sparsemax per (tree,depth) column via Michelot fixed-point.
// One wave per column, 4 elements/lane, shuffle reductions only (no LDS).
// Output TRANSPOSED [col][feature] bf16 hi/lo.
// ---------------------------------------------------------------------------
__global__ __launch_bounds__(256) void sparsemax_michelot(
    const float* __restrict__ fsl,       // [NF, NCOL]
    unsigned short* __restrict__ fs_hi,  // [NCOL, NF]
    unsigned short* __restrict__ fs_lo)  // [NCOL, NF]
{
    const int lane = threadIdx.x & 63;
    const int col  = blockIdx.x * 4 + (threadIdx.x >> 6);

    float x[4];
    #pragma unroll
    for (int j = 0; j < 4; j++)
        x[j] = fsl[(lane + 64 * j) * NCOL + col];

    // max over 256
    float mx = fmaxf(fmaxf(x[0], x[1]), fmaxf(x[2], x[3]));
    #pragma unroll
    for (int off = 32; off > 0; off >>= 1)
        mx = fmaxf(mx, __shfl_xor(mx, off));
    #pragma unroll
    for (int j = 0; j < 4; j++) x[j] -= mx;

    // tau_0 = (sum - 1)/256
    float s = (x[0] + x[1]) + (x[2] + x[3]);
    #pragma unroll
    for (int off = 32; off > 0; off >>= 1)
        s += __shfl_xor(s, off);
    float tau = (s - 1.0f) / 256.0f;

    // Michelot: S <- {x > tau}; tau <- (sum_S - 1)/|S|; stop when |S| stable.
    int prev = 256;
    for (int it = 0; it < 64; it++) {
        float ss = 0.0f, cc = 0.0f;
        #pragma unroll
        for (int j = 0; j < 4; j++)
            if (x[j] > tau) { ss += x[j]; cc += 1.0f; }
        #pragma unroll
        for (int off = 32; off > 0; off >>= 1) {
            ss += __shfl_xor(ss, off);
            cc += __shfl_xor(cc, off);
        }
        const int c = (int)cc;
        if (c == prev) break;
        prev = c;
        tau = (ss - 1.0f) / cc;
    }

    #pragma unroll
    for (int j = 0; j < 4; j++) {
        const float v = fmaxf(x[j] - tau, 0.0f);
        const unsigned short h = f2bf(v);
        fs_hi[col * NF + lane + 64 * j] = h;
        fs_lo[col * NF + lane + 64 * j] = f2bf(v - bf2f(h));
    }
}

// ---------------------------------------------------------------------------
// Kernel 2: fused split-bf16 MFMA GEMM + tree evaluation.
// Tile 64(M) x 96(N): 96 cols = 16 complete trees -> tree eval in epilogue,
// fv never hits global memory. A staged from fp32 x with in-register split.
// ---------------------------------------------------------------------------
#define TM 64
#define TN 96
#define TK 32
#define PK (TK + 8)   // padded LDS pitch (u16) to break bank conflicts

union SMem {
    struct {
        unsigned short Ah[TM][PK], Al[TM][PK];
        unsigned short Bh[TN][PK], Bl[TN][PK];
    } st;                                   // 25.0 KB (K-loop)
    struct {
        float fv[TM][TN + 1];               // 64 x 97
        float resp[16][NLEAF];              // 4 KB
    } ep;                                   // 28.25 KB (epilogue)
};

__global__ __launch_bounds__(256) void gemm_tree_kernel(
    const float* __restrict__ x,             // [NB, NF] fp32
    const unsigned short* __restrict__ Bh,   // fs hi [NCOL, NF]
    const unsigned short* __restrict__ Bl,   // fs lo [NCOL, NF]
    const float* __restrict__ thr,           // [NT, ND]
    const float* __restrict__ ltemp,         // [NT, ND]
    const float* __restrict__ resp_g,        // [NT, 1, NLEAF]
    float* __restrict__ out)                 // [NB, NT]
{
    __shared__ SMem sm;

    const int tid  = threadIdx.x;
    const int lane = tid & 63;
    const int w    = tid >> 6;
    const int wm   = w & 1;          // wave M pos (0..1) -> 32 rows
    const int wn   = w >> 1;         // wave N pos (0..1) -> 48 cols
    const int bm0  = blockIdx.y * TM;
    const int bn0  = blockIdx.x * TN;
    const int t0   = blockIdx.x * 16;    // first tree of this block

    const int l15  = lane & 15;
    const int quad = lane >> 4;

    // A staging coords: thread -> (row 0..63, kseg 0/8/16/24)
    const int arow  = tid >> 2;
    const int akseg = (tid & 3) * 8;
    // B staging coords: 128 threads hi, 128 threads lo; 32 rows x 32 k per pass
    const int bhalf = tid >> 7;
    const int brow  = (tid & 127) >> 2;
    const int bkseg = (tid & 3) * 8;

    f32x4 acc[2][3] = {};

    for (int k0 = 0; k0 < NF; k0 += TK) {
        // ---- A: load fp32, split to bf16 hi/lo in-register ----
        {
            const float4 v0 = *(const float4*)&x[(bm0 + arow) * NF + k0 + akseg];
            const float4 v1 = *(const float4*)&x[(bm0 + arow) * NF + k0 + akseg + 4];
            const float vv[8] = {v0.x, v0.y, v0.z, v0.w, v1.x, v1.y, v1.z, v1.w};
            u16x8 hi, lo;
            #pragma unroll
            for (int j = 0; j < 8; j++) {
                const unsigned short h = f2bf(vv[j]);
                hi[j] = h;
                lo[j] = f2bf(vv[j] - bf2f(h));
            }
            *(u16x8*)&sm.st.Ah[arow][akseg] = hi;
            *(u16x8*)&sm.st.Al[arow][akseg] = lo;
        }
        // ---- B: copy bf16 hi/lo tiles (96 rows x 32 k each) ----
        {
            const unsigned short* __restrict__ src = bhalf ? Bl : Bh;
            unsigned short (*dst)[PK] = bhalf ? sm.st.Bl : sm.st.Bh;
            #pragma unroll
            for (int c = 0; c < 3; c++) {
                const int row = c * 32 + brow;
                *(u16x8*)&dst[row][bkseg] =
                    *(const u16x8*)&src[(bn0 + row) * NF + k0 + bkseg];
            }
        }
        __syncthreads();

        #pragma unroll
        for (int im = 0; im < 2; im++) {
            const bf16x8 a_h = *(const bf16x8*)&sm.st.Ah[wm * 32 + im * 16 + l15][quad * 8];
            const bf16x8 a_l = *(const bf16x8*)&sm.st.Al[wm * 32 + im * 16 + l15][quad * 8];
            #pragma unroll
            for (int in = 0; in < 3; in++) {
                const bf16x8 b_h = *(const bf16x8*)&sm.st.Bh[wn * 48 + in * 16 + l15][quad * 8];
                const bf16x8 b_l = *(const bf16x8*)&sm.st.Bl[wn * 48 + in * 16 + l15][quad * 8];
                acc[im][in] = __builtin_amdgcn_mfma_f32_16x16x32_bf16(a_h, b_h, acc[im][in], 0, 0, 0);
                acc[im][in] = __builtin_amdgcn_mfma_f32_16x16x32_bf16(a_h, b_l, acc[im][in], 0, 0, 0);
                acc[im][in] = __builtin_amdgcn_mfma_f32_16x16x32_bf16(a_l, b_h, acc[im][in], 0, 0, 0);
            }
        }
        __syncthreads();
    }

    // ---- epilogue: fv -> LDS (C/D map: row=quad*4+r, col=l15), stage resp ----
    #pragma unroll
    for (int im = 0; im < 2; im++)
        #pragma unroll
        for (int in = 0; in < 3; in++)
            #pragma unroll
            for (int r = 0; r < 4; r++) {
                const int m = wm * 32 + im * 16 + quad * 4 + r;
                const int n = wn * 48 + in * 16 + l15;
                sm.ep.fv[m][n] = acc[im][in][r];
            }
    {
        const int tr  = tid >> 4;
        const int seg = (tid & 15) * 4;
        *(float4*)&sm.ep.resp[tr][seg] = *(const float4*)&resp_g[(t0 + tr) * NLEAF + seg];
    }
    __syncthreads();

    // ---- tree evaluation: 64 rows x 16 trees = 1024 items, 4 per thread ----
    #pragma unroll
    for (int i = 0; i < 4; i++) {
        const int item = tid + 256 * i;
        const int m    = item & 63;
        const int t16  = item >> 6;
        const int t    = t0 + t16;

        float sp[ND], sn[ND];
        #pragma unroll
        for (int d = 0; d < ND; d++) {
            const float f  = sm.ep.fv[m][t16 * ND + d];
            const float tl = (f - thr[t * ND + d]) * __expf(-ltemp[t * ND + d]);
            const float h  = 0.5f * tl;
            sp[d] = fminf(fmaxf(0.5f + h, 0.0f), 1.0f);  // bit==0 factor
            sn[d] = fminf(fmaxf(0.5f - h, 0.0f), 1.0f);  // bit==1 factor
        }

        float wleaf[NLEAF];
        wleaf[0] = 1.0f;
        #pragma unroll
        for (int d = 0; d < ND; d++) {
            const int half = 1 << d;
            #pragma unroll
            for (int c = 0; c < NLEAF / 2; c++) {
                if (c < half) {
                    const float base = wleaf[c];
                    wleaf[c + half] = base * sn[d];
                    wleaf[c]        = base * sp[d];
                }
            }
        }

        float a = 0.0f;
        #pragma unroll
        for (int c = 0; c < NLEAF; c++)
            a = fmaf(wleaf[c], sm.ep.resp[t16][c], a);

        out[(bm0 + m) * NT + t] = a;
    }
}

// ---------------------------------------------------------------------------
extern "C" void kernel_launch(void* const* d_in, const int* in_sizes, int n_in,
                              void* d_out, int out_size, void* d_ws, size_t ws_size,
                              hipStream_t stream)
{
    const float* x    = (const float*)d_in[0];  // [2048, 256]
    const float* resp = (const float*)d_in[1];  // [256, 1, 64]
    const float* fsl  = (const float*)d_in[2];  // [256, 256*6]
    const float* thr  = (const float*)d_in[3];  // [256, 6]
    const float* lt   = (const float*)d_in[4];  // [256, 6]
    float* out = (float*)d_out;                 // [2048, 256]

    unsigned short* fs_hi = (unsigned short*)d_ws;          // [NCOL, NF]
    unsigned short* fs_lo = fs_hi + (size_t)NCOL * NF;

    sparsemax_michelot<<<NCOL / 4, 256, 0, stream>>>(fsl, fs_hi, fs_lo);

    dim3 g(NCOL / TN, NB / TM);   // (16, 32)
    gemm_tree_kernel<<<g, 256, 0, stream>>>(x, fs_hi, fs_lo, thr, lt, resp, out);
}